// Round 13
// baseline (278.101 us; speedup 1.0000x reference)
//
#include <hip/hip_runtime.h>
#include <hip/hip_bf16.h>

#define SS 16
#define SP 65536   // 16^4

typedef __attribute__((ext_vector_type(8))) short short8;
typedef __attribute__((ext_vector_type(4))) float f32x4;

// ---------------------------------------------------------------------------
// Device prep bodies (verified r3/r5/r9)
// ---------------------------------------------------------------------------
__device__ inline void build_xim_dev(int t, const float* __restrict__ X,
                                     __hip_bfloat16* __restrict__ Xim)
{
    int g   = t & 3;
    int pos = t >> 2;
    int w2 = pos & 15, h2 = (pos >> 4) & 15;
    const float* xp = X + ((size_t)(pos >> 8) << 8);
    __hip_bfloat16 vals[8];
    #pragma unroll
    for (int j = 0; j < 8; ++j) {
        int s = g*8 + j;
        float v = 0.f;
        if (s < 25) {
            int hh = h2 + s/5 - 2, ww = w2 + s%5 - 2;
            if ((unsigned)hh < 16u && (unsigned)ww < 16u)
                v = xp[hh*16 + ww];
        }
        vals[j] = __float2bfloat16(v);
    }
    *reinterpret_cast<short8*>(Xim + (size_t)t * 8) = *reinterpret_cast<const short8*>(vals);
}

template<int KA, int KB>
__device__ inline void prep_bl1_dev(int t, const float* __restrict__ W,
                                    __hip_bfloat16* __restrict__ Bf)
{
    constexpr int PA = KA/2, PB = KB/2;
    int lane = t & 63, p = t >> 6;
    int pi = p/5, pj = p%5;
    int n = lane & 15;
    __hip_bfloat16 vals[8];
    #pragma unroll
    for (int j = 0; j < 8; ++j) {
        int s = (lane >> 4)*8 + j;
        float v = 0.f;
        if (s < 25) {
            int kk = s/5, ll = s%5;
            if (n < 8) {
                int i = pi - 2 + PA, jj = pj - 2 + PB;
                if ((unsigned)i < (unsigned)KA && (unsigned)jj < (unsigned)KB)
                    v = W[(((n*KA + i)*KB + jj)*5 + kk)*5 + ll];
            } else {
                int k2 = kk - 2 + PA, l2 = ll - 2 + PB;
                if ((unsigned)k2 < (unsigned)KA && (unsigned)l2 < (unsigned)KB)
                    v = W[((((n-8)*KA + k2)*KB + l2)*5 + pi)*5 + pj];
            }
        }
        vals[j] = __float2bfloat16(v);
    }
    *reinterpret_cast<short8*>(Bf + (size_t)t * 8) = *reinterpret_cast<const short8*>(vals);
}

template<int O, int KA, int KB>
__device__ inline void prep_bfrag_dev(int t, const float* __restrict__ W,
                                      __hip_bfloat16* __restrict__ Bws)
{
    constexpr int PA = KA/2, PB = KB/2;
    int lane = t & 63;
    int f = (t >> 6) % 13;
    int p = t / (64*13);
    int pi = p/5, pj = p%5;
    bool c1a = (pi >= 2-PA && pi <= 2+PA && pj >= 2-PB && pj <= 2+PB);
    int slen = c1a ? 400 : KA*KB*16;
    int n = lane & 15;
    __hip_bfloat16 vals[8];
    #pragma unroll
    for (int j = 0; j < 8; ++j) {
        int kk = f*32 + ((lane>>4)*8) + j;
        float v = 0.f;
        if (kk < slen) {
            int sp = kk >> 4, c = kk & 15;
            int dsh, dsw;
            if (c1a) { dsh = sp/5 - 2;  dsw = sp%5 - 2;  }
            else     { dsh = sp/KB - PA; dsw = sp%KB - PB; }
            if (n < 8) {
                if (c1a && n < O)
                    v = W[((((size_t)(n*16 + c)*KA + (pi-2+PA))*KB + (pj-2+PB))*5 + (dsh+2))*5 + (dsw+2)];
            } else {
                int o = n - 8;
                if (o < O && dsh >= -PA && dsh <= PA && dsw >= -PB && dsw <= PB)
                    v = W[((((size_t)(o*16 + c)*KA + (dsh+PA))*KB + (dsw+PB))*5 + pi)*5 + pj];
            }
        }
        vals[j] = __float2bfloat16(v);
    }
    *reinterpret_cast<short8*>(Bws + (size_t)t * 8) = *reinterpret_cast<const short8*>(vals);
}

__device__ inline void prep_bl3_dev(int t, const float* __restrict__ W,
                                    __hip_bfloat16* __restrict__ Bf)
{
    int lane = t & 63;
    int f = (t >> 6) % 20;
    int p = t / (64*20);
    int pi = p/5, pj = p%5;
    int n = lane & 15;
    __hip_bfloat16 vals[8];
    #pragma unroll
    for (int j = 0; j < 8; ++j) {
        int kk = f*32 + ((lane>>4)*8) + j;    // < 640
        int s = kk >> 4, c = kk & 15;
        int shidx = s >> 3;
        int swidx = s & 7;
        float v = 0.f;
        if (n < 8) {
            int dlt = n & 3;
            int sw = swidx - 2 - dlt;
            int sh = shidx - 2;
            if (sw >= -2 && sw <= 2) {
                if (n < 4)
                    v = W[(((c*5 + pi)*5 + pj)*5 + (sh+2))*5 + (sw+2)];
                else
                    v = W[(((c*5 + (sh+2))*5 + (sw+2))*5 + pi)*5 + pj];
            }
        }
        vals[j] = __float2bfloat16(v);
    }
    *reinterpret_cast<short8*>(Bf + (size_t)t * 8) = *reinterpret_cast<const short8*>(vals);
}

// One dispatch: Xim build + all 5 B tables
__global__ __launch_bounds__(256)
void fused_pre(const float* __restrict__ x, int ximTotal,
               const float* __restrict__ w00, const float* __restrict__ w01,
               const float* __restrict__ w10, const float* __restrict__ w11,
               const float* __restrict__ w2,
               __hip_bfloat16* __restrict__ Xim,
               __hip_bfloat16* __restrict__ Bl1a, __hip_bfloat16* __restrict__ Bl1b,
               __hip_bfloat16* __restrict__ Bw10, __hip_bfloat16* __restrict__ Bw11,
               __hip_bfloat16* __restrict__ Bl3)
{
    int t = blockIdx.x * 256 + threadIdx.x;
    if (t < ximTotal) { build_xim_dev(t, x, Xim); return; }
    t -= ximTotal;
    if (t < 1600)  { prep_bl1_dev<3,3>(t, w00, Bl1a); return; }
    t -= 1600;
    if (t < 1600)  { prep_bl1_dev<5,5>(t, w01, Bl1b); return; }
    t -= 1600;
    if (t < 20800) { prep_bfrag_dev<8,3,3>(t, w10, Bw10); return; }
    t -= 20800;
    if (t < 20800) { prep_bfrag_dev<8,5,5>(t, w11, Bw11); return; }
    t -= 20800;
    if (t < 32000) { prep_bl3_dev(t, w2, Bl3); }
}

// ---------------------------------------------------------------------------
// Layer-1 MFMA (r3, measured ~25 us)
// ---------------------------------------------------------------------------
__global__ __launch_bounds__(256)
void conv_mfma_l1(const __hip_bfloat16* __restrict__ Xim,
                  const __hip_bfloat16* __restrict__ B0,
                  const __hip_bfloat16* __restrict__ B1,
                  const float* __restrict__ bias0,
                  const float* __restrict__ bias1,
                  __hip_bfloat16* __restrict__ Y)
{
    const int tid = threadIdx.x, lane = tid & 63, wid = tid >> 6;
    int blk = (blockIdx.x & 7) * (gridDim.x >> 3) + (blockIdx.x >> 3);
    const int w1 = blk & 15, h1 = (blk >> 4) & 15, b = blk >> 8;
    const int g = lane >> 4, lane15 = lane & 15;

    f32x4 acc0[4] = {{0,0,0,0},{0,0,0,0},{0,0,0,0},{0,0,0,0}};
    f32x4 acc1[4] = {{0,0,0,0},{0,0,0,0},{0,0,0,0},{0,0,0,0}};
    const short8* BB0 = reinterpret_cast<const short8*>(B0);
    const short8* BB1 = reinterpret_cast<const short8*>(B1);

    for (int p = 0; p < 25; ++p) {
        int hh = h1 + p/5 - 2, ww = w1 + p%5 - 2;
        if ((unsigned)hh >= 16u || (unsigned)ww >= 16u) continue;
        const short8* ap = reinterpret_cast<const short8*>(Xim)
                         + ((size_t)((b*16 + hh)*16 + ww) << 10);
        short8 b0 = BB0[p*64 + lane];
        short8 b1 = BB1[p*64 + lane];
        #pragma unroll
        for (int mt = 0; mt < 4; ++mt) {
            short8 a = ap[(((wid*4 + mt)*16 + lane15) << 2) + g];
            acc0[mt] = __builtin_amdgcn_mfma_f32_16x16x32_bf16(a, b0, acc0[mt], 0, 0, 0);
            acc1[mt] = __builtin_amdgcn_mfma_f32_16x16x32_bf16(a, b1, acc1[mt], 0, 0, 0);
        }
    }

    const int o = lane15 & 7;
    const float bv0 = bias0[o], bv1 = bias1[o];
    #pragma unroll
    for (int mt = 0; mt < 4; ++mt) {
        #pragma unroll
        for (int r = 0; r < 4; ++r) {
            float own0 = acc0[mt][r], oth0 = __shfl_xor(own0, 8);
            float own1 = acc1[mt][r], oth1 = __shfl_xor(own1, 8);
            if (lane15 < 8) {
                float y0 = fmaxf(own0 + bv0, 0.f) + fmaxf(oth0 + bv0, 0.f);
                float y1 = fmaxf(own1 + bv1, 0.f) + fmaxf(oth1 + bv1, 0.f);
                int h2 = wid*4 + mt, w2v = g*4 + r;
                size_t pos = ((size_t)blk << 8) + h2*16 + w2v;
                Y[pos*16 + o]     = __float2bfloat16(y0);
                Y[pos*16 + 8 + o] = __float2bfloat16(y1);
            }
        }
    }
}

// ---------------------------------------------------------------------------
// L2 with K-SPLIT across waves (r9-proven technique, applied to L2):
// wave wid owns frags f = ff*4 + wid and computes ALL 16 h2-tiles per frag
// (B loads/wave cut 4x: w11 B-vmem 5.3 -> 1.3 MB/CU; LDS/MFMA unchanged).
// Cross-wave K-reduction: 4 literal-unrolled rounds through the plane buffer
// (12.3 KB/round); owner sums into literal-indexed out[4] (rule-#20 safe).
// ---------------------------------------------------------------------------
__device__ inline void load_plane_regs(const __hip_bfloat16* __restrict__ X,
                                       int b, int h1, int w1, int p, int tid,
                                       short8& s0, short8& s1)
{
    int pi = p/5, pj = p%5;
    int hh = h1 + pi - 2, ww = w1 + pj - 2;
    short8 z = {};
    if ((unsigned)hh < 16u && (unsigned)ww < 16u) {
        const short8* src = reinterpret_cast<const short8*>(X)
                          + ((size_t)((b*16 + hh)*16 + ww) << 9);
        s0 = src[tid];
        s1 = src[tid + 256];
    } else { s0 = z; s1 = z; }
}

template<int O, int KA, int KB>
__device__ inline void conv_body_ks(const __hip_bfloat16* __restrict__ X,
                                    const __hip_bfloat16* __restrict__ Bws,
                                    const float* __restrict__ bias,
                                    __hip_bfloat16* __restrict__ Y, int obase,
                                    int blk, int tid, char* lbuf)
{
    constexpr int PA = KA/2, PB = KB/2;
    constexpr bool FULLALL = (KA == 5 && KB == 5);
    constexpr int NFC = 13;
    constexpr int NFO = (KA*KB*16 + 31)/32;

    const int lane = tid & 63, wid = tid >> 6;
    const int w1 = blk & 15, h1 = (blk >> 4) & 15, b = blk >> 8;
    const int g = lane >> 4, lane15 = lane & 15;

    for (int i = tid; i < 3200; i += 256) reinterpret_cast<int*>(lbuf)[i] = 0;

    // own-frag A offsets (f = ff*4 + wid)
    unsigned offsC[4];
    #pragma unroll
    for (int ff = 0; ff < 4; ++ff) {
        int f = ff*4 + wid;
        unsigned off = 0;
        if (f < NFC) {
            int kk = f*32 + g*8;
            if (kk < 400) {
                int sp = kk >> 4, half = (kk >> 3) & 1;
                int dsh = sp/5 - 2, dsw = sp%5 - 2;
                off = (unsigned)(half*6400 + ((dsh+2)*20 + (dsw+2))*16);
            }
        }
        offsC[ff] = off;
    }
    unsigned offsO[2];
    if (!FULLALL) {
        #pragma unroll
        for (int ff = 0; ff < 2; ++ff) {
            int f = ff*4 + wid;
            unsigned off = 0;
            if (f < NFO) {
                int kk = f*32 + g*8;
                if (kk < KA*KB*16) {
                    int sp = kk >> 4, half = (kk >> 3) & 1;
                    int dsh = sp/KB - PA, dsw = sp%KB - PB;
                    off = (unsigned)(half*6400 + ((dsh+2)*20 + (dsw+2))*16);
                }
            }
            offsO[ff] = off;
        }
    }

    f32x4 acc[16] = {};
    const unsigned aterm = (unsigned)(lane15*16);

    const int dst0 = (tid&1)*6400 + (((tid>>1)>>4)+2)*320 + (((tid>>1)&15)+2)*16;
    const int dst1 = dst0 + 2560;

    short8 st0, st1;
    load_plane_regs(X, b, h1, w1, 0, tid, st0, st1);

    for (int p = 0; p < 25; ++p) {
        __syncthreads();
        *reinterpret_cast<short8*>(lbuf + dst0) = st0;
        *reinterpret_cast<short8*>(lbuf + dst1) = st1;
        __syncthreads();
        if (p < 24) load_plane_regs(X, b, h1, w1, p+1, tid, st0, st1);

        int pi = p/5, pj = p%5;
        const short8* bp = reinterpret_cast<const short8*>(Bws) + (size_t)p*13*64 + lane;
        bool center = FULLALL || (pi >= 2-PA && pi <= 2+PA && pj >= 2-PB && pj <= 2+PB);
        if (center) {
            #pragma unroll
            for (int ff = 0; ff < 4; ++ff) {
                int f = ff*4 + wid;
                if (f < NFC) {                        // wave-uniform
                    short8 bf = bp[f*64];
                    #pragma unroll
                    for (int mt = 0; mt < 16; ++mt) {
                        short8 a = *reinterpret_cast<const short8*>(
                            lbuf + offsC[ff] + aterm + mt*320);
                        acc[mt] = __builtin_amdgcn_mfma_f32_16x16x32_bf16(a, bf, acc[mt], 0, 0, 0);
                    }
                }
            }
        } else {
            #pragma unroll
            for (int ff = 0; ff < 2; ++ff) {
                int f = ff*4 + wid;
                if (f < NFO) {                        // wave-uniform
                    short8 bf = bp[f*64];
                    #pragma unroll
                    for (int mt = 0; mt < 16; ++mt) {
                        short8 a = *reinterpret_cast<const short8*>(
                            lbuf + offsO[ff] + aterm + mt*320);
                        acc[mt] = __builtin_amdgcn_mfma_f32_16x16x32_bf16(a, bf, acc[mt], 0, 0, 0);
                    }
                }
            }
        }
    }

    // Cross-wave K-reduction: round r gathers tiles r*4..r*4+3 to wave r.
    f32x4 out[4];
    f32x4* red = reinterpret_cast<f32x4*>(lbuf);
    __syncthreads();
    #pragma unroll
    for (int r = 0; r < 4; ++r) {
        if (wid != r) {
            int ws = wid - (wid > r ? 1 : 0);         // 0..2
            #pragma unroll
            for (int tl = 0; tl < 4; ++tl)
                red[(ws*4 + tl)*64 + lane] = acc[r*4 + tl];
        }
        __syncthreads();
        if (wid == r) {
            #pragma unroll
            for (int tl = 0; tl < 4; ++tl) {
                f32x4 s = acc[r*4 + tl];
                #pragma unroll
                for (int ws = 0; ws < 3; ++ws)
                    s = s + red[(ws*4 + tl)*64 + lane];
                out[tl] = s;
            }
        }
        __syncthreads();
    }

    // Epilogue: wave wid owns h2 = wid*4 + tl (identical to r3 mapping).
    const int o = lane15 & 7;
    const float bv = (o < O) ? bias[o] : 0.f;
    #pragma unroll
    for (int tl = 0; tl < 4; ++tl) {
        #pragma unroll
        for (int r = 0; r < 4; ++r) {
            float own = out[tl][r];
            float oth = __shfl_xor(own, 8);
            if (lane15 < 8 && o < O) {
                float y = fmaxf(own + bv, 0.f) + fmaxf(oth + bv, 0.f);
                int h2 = wid*4 + tl, w2 = g*4 + r;
                size_t pos = ((size_t)blk << 8) + h2*16 + w2;
                Y[pos*16 + obase + o] = __float2bfloat16(y);
            }
        }
    }
}

__global__ __launch_bounds__(256)
void conv_mfma_l2ka(const __hip_bfloat16* __restrict__ X,
                    const __hip_bfloat16* __restrict__ Bws,
                    const float* __restrict__ bias,
                    __hip_bfloat16* __restrict__ Y)
{
    __shared__ __align__(16) char lbuf[12800];
    int blk = (blockIdx.x & 7) * (gridDim.x >> 3) + (blockIdx.x >> 3);
    conv_body_ks<8,3,3>(X, Bws, bias, Y, 0, blk, threadIdx.x, lbuf);
}

__global__ __launch_bounds__(256)
void conv_mfma_l2kb(const __hip_bfloat16* __restrict__ X,
                    const __hip_bfloat16* __restrict__ Bws,
                    const float* __restrict__ bias,
                    __hip_bfloat16* __restrict__ Y)
{
    __shared__ __align__(16) char lbuf[12800];
    int blk = (blockIdx.x & 7) * (gridDim.x >> 3) + (blockIdx.x >> 3);
    conv_body_ks<8,5,5>(X, Bws, bias, Y, 8, blk, threadIdx.x, lbuf);
}

// ---------------------------------------------------------------------------
// L3 delta-packed MFMA with 4-way K-split across waves (r9, verified ~28 us)
// ---------------------------------------------------------------------------
__device__ inline void load_plane_l3(const __hip_bfloat16* __restrict__ X,
                                     int b, int h1, int w1, int p, int tid,
                                     short8& s0, short8& s1)
{
    int pi = p/5, pj = p%5;
    int hh = h1 + pi - 2, ww = w1 + pj - 2;
    short8 z = {};
    if ((unsigned)hh < 16u && (unsigned)ww < 16u) {
        const short8* src = reinterpret_cast<const short8*>(X)
                          + ((size_t)((b*16 + hh)*16 + ww) << 9);
        s0 = src[tid*2];
        s1 = src[tid*2 + 1];
    } else { s0 = z; s1 = z; }
}

__global__ __launch_bounds__(256)
void conv_mfma_l3k(const __hip_bfloat16* __restrict__ X,
                   const __hip_bfloat16* __restrict__ Bf,
                   const float* __restrict__ bias,
                   float* __restrict__ Yout)
{
    __shared__ __align__(16) char lbuf[16384];

    const int tid = threadIdx.x, lane = tid & 63, wid = tid >> 6;
    int blk = (blockIdx.x & 7) * (gridDim.x >> 3) + (blockIdx.x >> 3);
    const int w1 = blk & 15, h1 = (blk >> 4) & 15, b = blk >> 8;
    const int g = lane >> 4, lane15 = lane & 15;

    for (int i = tid; i < 3200; i += 256) reinterpret_cast<int*>(lbuf)[i] = 0;

    unsigned offA[5];
    #pragma unroll
    for (int fl = 0; fl < 5; ++fl) {
        int fg = wid*5 + fl;
        int s     = fg*2 + (g >> 1);
        int chalf = g & 1;
        int shidx = s >> 3;
        int swidx = s & 7;
        int row   = lane15 + shidx;
        unsigned a = (unsigned)(row*640 + swidx*32 + chalf*16);
        offA[fl] = a ^ (((unsigned)(row & 7)) << 4);
    }

    const int srow = (tid >> 4) + 2;
    const unsigned wswz = ((unsigned)(srow & 7)) << 4;
    const unsigned wp0 = ((unsigned)(srow*640 + ((tid & 15) + 2)*32)) ^ wswz;

    f32x4 acc[4] = {{0,0,0,0},{0,0,0,0},{0,0,0,0},{0,0,0,0}};

    short8 st0, st1;
    load_plane_l3(X, b, h1, w1, 0, tid, st0, st1);

    for (int p = 0; p < 25; ++p) {
        __syncthreads();
        *reinterpret_cast<short8*>(lbuf + wp0)        = st0;
        *reinterpret_cast<short8*>(lbuf + (wp0^16u))  = st1;
        __syncthreads();
        if (p < 24) load_plane_l3(X, b, h1, w1, p+1, tid, st0, st1);

        const short8* bpp = reinterpret_cast<const short8*>(Bf)
                          + (size_t)p*20*64 + (size_t)wid*5*64 + lane;
        #pragma unroll
        for (int fl = 0; fl < 5; ++fl) {
            short8 bf = bpp[fl*64];
            #pragma unroll
            for (int q = 0; q < 4; ++q) {
                short8 a = *reinterpret_cast<const short8*>(lbuf + offA[fl] + q*128);
                acc[q] = __builtin_amdgcn_mfma_f32_16x16x32_bf16(a, bf, acc[q], 0, 0, 0);
            }
        }
    }

    __syncthreads();
    f32x4* red = reinterpret_cast<f32x4*>(lbuf);
    #pragma unroll
    for (int q = 0; q < 4; ++q)
        red[(wid*4 + q)*64 + lane] = acc[q];
    __syncthreads();

    f32x4 tot = red[wid*64 + lane];
    #pragma unroll
    for (int w = 1; w < 4; ++w)
        tot = tot + red[(w*4 + wid)*64 + lane];

    const float bv = bias[0];
    #pragma unroll
    for (int r = 0; r < 4; ++r) {
        float own = tot[r];
        float oth = __shfl_xor(own, 4);
        if (lane15 < 4) {
            float y = fmaxf(own + bv, 0.f) + fmaxf(oth + bv, 0.f);
            int h2 = g*4 + r, w2v = wid*4 + lane15;
            Yout[((size_t)blk << 8) + h2*16 + w2v] = y;
        }
    }
}

// ---------------------------------------------------------------------------
extern "C" void kernel_launch(void* const* d_in, const int* in_sizes, int n_in,
                              void* d_out, int out_size, void* d_ws, size_t ws_size,
                              hipStream_t stream) {
    const float* x   = (const float*)d_in[0];
    const float* w00 = (const float*)d_in[1];
    const float* b00 = (const float*)d_in[2];
    const float* w01 = (const float*)d_in[3];
    const float* b01 = (const float*)d_in[4];
    const float* w10 = (const float*)d_in[5];
    const float* b10 = (const float*)d_in[6];
    const float* w11 = (const float*)d_in[7];
    const float* b11 = (const float*)d_in[8];
    const float* w2  = (const float*)d_in[9];
    const float* b2  = (const float*)d_in[10];

    const int B = in_sizes[0] / SP;   // 4

    __hip_bfloat16* X1   = (__hip_bfloat16*)d_ws;                 // B*SP*16
    __hip_bfloat16* X2   = X1 + (size_t)B * SP * 16;              // B*SP*16
    __hip_bfloat16* Bw10 = X2 + (size_t)B * SP * 16;              // 25*13*64*8
    __hip_bfloat16* Bw11 = Bw10 + 25*13*64*8;
    __hip_bfloat16* Bl3  = Bw11 + 25*13*64*8;                     // 25*20*64*8
    __hip_bfloat16* Bl1a = Bl3  + 25*20*64*8;                     // 25*64*8
    __hip_bfloat16* Bl1b = Bl1a + 25*64*8;
    __hip_bfloat16* Xim  = Bl1b + 25*64*8;                        // B*SP*32

    const int ximTotal = B * SP * 4;                              // 1048576
    const int preTotal = ximTotal + 76800;
    hipLaunchKernelGGL(fused_pre, dim3((preTotal + 255)/256), dim3(256), 0, stream,
                       x, ximTotal, w00, w01, w10, w11, w2,
                       Xim, Bl1a, Bl1b, Bw10, Bw11, Bl3);

    dim3 block(256), grid(B * 256);
    hipLaunchKernelGGL(conv_mfma_l1, grid, block, 0, stream,
                       Xim, Bl1a, Bl1b, b00, b01, X1);

    hipLaunchKernelGGL(conv_mfma_l2ka, grid, block, 0, stream,
                       X1, Bw10, b10, X2);
    hipLaunchKernelGGL(conv_mfma_l2kb, grid, block, 0, stream,
                       X1, Bw11, b11, X2);

    hipLaunchKernelGGL(conv_mfma_l3k, grid, block, 0, stream,
                       X2, Bl3, b2, (float*)d_out);
}

// Round 14
// 212.481 us; speedup vs baseline: 1.3088x; 1.3088x over previous
//
#include <hip/hip_runtime.h>
#include <hip/hip_bf16.h>

#define SS 16
#define SP 65536   // 16^4

typedef __attribute__((ext_vector_type(8))) short short8;
typedef __attribute__((ext_vector_type(4))) float f32x4;

// ---------------------------------------------------------------------------
// Xim: [b][h1][w1][h2][w2][32] bf16. Slot s = k*5+l <-> inner shift (k-2, l-2)
// ---------------------------------------------------------------------------
__global__ __launch_bounds__(256)
void build_xim(const float* __restrict__ X, __hip_bfloat16* __restrict__ Xim, int total)
{
    int t = blockIdx.x * 256 + threadIdx.x;       // t = pos*4 + g
    if (t >= total) return;
    int g   = t & 3;
    int pos = t >> 2;
    int w2 = pos & 15, h2 = (pos >> 4) & 15;
    const float* xp = X + ((size_t)(pos >> 8) << 8);
    __hip_bfloat16 vals[8];
    #pragma unroll
    for (int j = 0; j < 8; ++j) {
        int s = g*8 + j;
        float v = 0.f;
        if (s < 25) {
            int hh = h2 + s/5 - 2, ww = w2 + s%5 - 2;
            if ((unsigned)hh < 16u && (unsigned)ww < 16u)
                v = xp[hh*16 + ww];
        }
        vals[j] = __float2bfloat16(v);
    }
    *reinterpret_cast<short8*>(Xim + (size_t)t * 8) = *reinterpret_cast<const short8*>(vals);
}

// ---------------------------------------------------------------------------
// Prep device functions (bodies of the verified r3/r5 prep kernels)
// ---------------------------------------------------------------------------
template<int KA, int KB>
__device__ inline void prep_bl1_dev(int t, const float* __restrict__ W,
                                    __hip_bfloat16* __restrict__ Bf)
{
    constexpr int PA = KA/2, PB = KB/2;
    int lane = t & 63, p = t >> 6;
    int pi = p/5, pj = p%5;
    int n = lane & 15;
    __hip_bfloat16 vals[8];
    #pragma unroll
    for (int j = 0; j < 8; ++j) {
        int s = (lane >> 4)*8 + j;
        float v = 0.f;
        if (s < 25) {
            int kk = s/5, ll = s%5;
            if (n < 8) {
                int i = pi - 2 + PA, jj = pj - 2 + PB;
                if ((unsigned)i < (unsigned)KA && (unsigned)jj < (unsigned)KB)
                    v = W[(((n*KA + i)*KB + jj)*5 + kk)*5 + ll];
            } else {
                int k2 = kk - 2 + PA, l2 = ll - 2 + PB;
                if ((unsigned)k2 < (unsigned)KA && (unsigned)l2 < (unsigned)KB)
                    v = W[((((n-8)*KA + k2)*KB + l2)*5 + pi)*5 + pj];
            }
        }
        vals[j] = __float2bfloat16(v);
    }
    *reinterpret_cast<short8*>(Bf + (size_t)t * 8) = *reinterpret_cast<const short8*>(vals);
}

// r3 compact-stream L2 B fragments (center: 400-slot union; else KA*KB*16)
template<int O, int KA, int KB>
__device__ inline void prep_bfrag_dev(int t, const float* __restrict__ W,
                                      __hip_bfloat16* __restrict__ Bws)
{
    constexpr int PA = KA/2, PB = KB/2;
    int lane = t & 63;
    int f = (t >> 6) % 13;
    int p = t / (64*13);
    int pi = p/5, pj = p%5;
    bool c1a = (pi >= 2-PA && pi <= 2+PA && pj >= 2-PB && pj <= 2+PB);
    int slen = c1a ? 400 : KA*KB*16;
    int n = lane & 15;
    __hip_bfloat16 vals[8];
    #pragma unroll
    for (int j = 0; j < 8; ++j) {
        int kk = f*32 + ((lane>>4)*8) + j;
        float v = 0.f;
        if (kk < slen) {
            int sp = kk >> 4, c = kk & 15;
            int dsh, dsw;
            if (c1a) { dsh = sp/5 - 2;  dsw = sp%5 - 2;  }
            else     { dsh = sp/KB - PA; dsw = sp%KB - PB; }
            if (n < 8) {
                if (c1a && n < O)
                    v = W[((((size_t)(n*16 + c)*KA + (pi-2+PA))*KB + (pj-2+PB))*5 + (dsh+2))*5 + (dsw+2)];
            } else {
                int o = n - 8;
                if (o < O && dsh >= -PA && dsh <= PA && dsw >= -PB && dsw <= PB)
                    v = W[((((size_t)(o*16 + c)*KA + (dsh+PA))*KB + (dsw+PB))*5 + pi)*5 + pj];
            }
        }
        vals[j] = __float2bfloat16(v);
    }
    *reinterpret_cast<short8*>(Bws + (size_t)t * 8) = *reinterpret_cast<const short8*>(vals);
}

// L3 delta-packed B fragments: 20 frags/plane, k = (s_h 5, s_w' 8, c 16)
__device__ inline void prep_bl3_dev(int t, const float* __restrict__ W,
                                    __hip_bfloat16* __restrict__ Bf)
{
    int lane = t & 63;
    int f = (t >> 6) % 20;
    int p = t / (64*20);
    int pi = p/5, pj = p%5;
    int n = lane & 15;
    __hip_bfloat16 vals[8];
    #pragma unroll
    for (int j = 0; j < 8; ++j) {
        int kk = f*32 + ((lane>>4)*8) + j;    // < 640
        int s = kk >> 4, c = kk & 15;
        int shidx = s >> 3;                   // 0..4  (s_h = shidx-2)
        int swidx = s & 7;                    // 0..7  (s_w' = swidx-2)
        float v = 0.f;
        if (n < 8) {
            int dlt = n & 3;
            int sw = swidx - 2 - dlt;
            int sh = shidx - 2;
            if (sw >= -2 && sw <= 2) {
                if (n < 4)
                    v = W[(((c*5 + pi)*5 + pj)*5 + (sh+2))*5 + (sw+2)];
                else
                    v = W[(((c*5 + (sh+2))*5 + (sw+2))*5 + pi)*5 + pj];
            }
        }
        vals[j] = __float2bfloat16(v);
    }
    *reinterpret_cast<short8*>(Bf + (size_t)t * 8) = *reinterpret_cast<const short8*>(vals);
}

// One dispatch for all 5 prep tables (76800 threads total)
__global__ __launch_bounds__(256)
void fused_prep(const float* __restrict__ w00, const float* __restrict__ w01,
                const float* __restrict__ w10, const float* __restrict__ w11,
                const float* __restrict__ w2,
                __hip_bfloat16* __restrict__ Bl1a, __hip_bfloat16* __restrict__ Bl1b,
                __hip_bfloat16* __restrict__ Bw10, __hip_bfloat16* __restrict__ Bw11,
                __hip_bfloat16* __restrict__ Bl3)
{
    int t = blockIdx.x * 256 + threadIdx.x;
    if (t < 1600)  { prep_bl1_dev<3,3>(t, w00, Bl1a); return; }
    t -= 1600;
    if (t < 1600)  { prep_bl1_dev<5,5>(t, w01, Bl1b); return; }
    t -= 1600;
    if (t < 20800) { prep_bfrag_dev<8,3,3>(t, w10, Bw10); return; }
    t -= 20800;
    if (t < 20800) { prep_bfrag_dev<8,5,5>(t, w11, Bw11); return; }
    t -= 20800;
    if (t < 32000) { prep_bl3_dev(t, w2, Bl3); }
}

// ---------------------------------------------------------------------------
// Layer-1 MFMA: no LDS, A direct from Xim, two B streams share A. (r3, fast)
// ---------------------------------------------------------------------------
__global__ __launch_bounds__(256)
void conv_mfma_l1(const __hip_bfloat16* __restrict__ Xim,
                  const __hip_bfloat16* __restrict__ B0,
                  const __hip_bfloat16* __restrict__ B1,
                  const float* __restrict__ bias0,
                  const float* __restrict__ bias1,
                  __hip_bfloat16* __restrict__ Y)
{
    const int tid = threadIdx.x, lane = tid & 63, wid = tid >> 6;
    int blk = (blockIdx.x & 7) * (gridDim.x >> 3) + (blockIdx.x >> 3);
    const int w1 = blk & 15, h1 = (blk >> 4) & 15, b = blk >> 8;
    const int g = lane >> 4, lane15 = lane & 15;

    f32x4 acc0[4] = {{0,0,0,0},{0,0,0,0},{0,0,0,0},{0,0,0,0}};
    f32x4 acc1[4] = {{0,0,0,0},{0,0,0,0},{0,0,0,0},{0,0,0,0}};
    const short8* BB0 = reinterpret_cast<const short8*>(B0);
    const short8* BB1 = reinterpret_cast<const short8*>(B1);

    for (int p = 0; p < 25; ++p) {
        int hh = h1 + p/5 - 2, ww = w1 + p%5 - 2;
        if ((unsigned)hh >= 16u || (unsigned)ww >= 16u) continue;
        const short8* ap = reinterpret_cast<const short8*>(Xim)
                         + ((size_t)((b*16 + hh)*16 + ww) << 10);
        short8 b0 = BB0[p*64 + lane];
        short8 b1 = BB1[p*64 + lane];
        #pragma unroll
        for (int mt = 0; mt < 4; ++mt) {
            short8 a = ap[(((wid*4 + mt)*16 + lane15) << 2) + g];
            acc0[mt] = __builtin_amdgcn_mfma_f32_16x16x32_bf16(a, b0, acc0[mt], 0, 0, 0);
            acc1[mt] = __builtin_amdgcn_mfma_f32_16x16x32_bf16(a, b1, acc1[mt], 0, 0, 0);
        }
    }

    const int o = lane15 & 7;
    const float bv0 = bias0[o], bv1 = bias1[o];
    #pragma unroll
    for (int mt = 0; mt < 4; ++mt) {
        #pragma unroll
        for (int r = 0; r < 4; ++r) {
            float own0 = acc0[mt][r], oth0 = __shfl_xor(own0, 8);
            float own1 = acc1[mt][r], oth1 = __shfl_xor(own1, 8);
            if (lane15 < 8) {
                float y0 = fmaxf(own0 + bv0, 0.f) + fmaxf(oth0 + bv0, 0.f);
                float y1 = fmaxf(own1 + bv1, 0.f) + fmaxf(oth1 + bv1, 0.f);
                int h2 = wid*4 + mt, w2v = g*4 + r;
                size_t pos = ((size_t)blk << 8) + h2*16 + w2v;
                Y[pos*16 + o]     = __float2bfloat16(y0);
                Y[pos*16 + 8 + o] = __float2bfloat16(y1);
            }
        }
    }
}

// ---------------------------------------------------------------------------
// Layer-2 MFMA conv (r3 split template, measured 83/50 us — LDS-feed-bound
// structural floor; 8 alternative structures all regressed:
// merged-16 224, batch-M 279, 2-pos 193, exec-mask 135, 32x32(capped) 753,
// 32x32(free) 157, l2both 147, K-split 185)
// ---------------------------------------------------------------------------
__device__ inline void load_plane_regs(const __hip_bfloat16* __restrict__ X,
                                       int b, int h1, int w1, int p, int tid,
                                       short8& s0, short8& s1)
{
    int pi = p/5, pj = p%5;
    int hh = h1 + pi - 2, ww = w1 + pj - 2;
    short8 z = {};
    if ((unsigned)hh < 16u && (unsigned)ww < 16u) {
        const short8* src = reinterpret_cast<const short8*>(X)
                          + ((size_t)((b*16 + hh)*16 + ww) << 9);
        s0 = src[tid];
        s1 = src[tid + 256];
    } else { s0 = z; s1 = z; }
}

template<int O, int KA, int KB, bool OUTBF16>
__global__ __launch_bounds__(256)
void conv_mfma(const __hip_bfloat16* __restrict__ X,
               const __hip_bfloat16* __restrict__ Bws,
               const float* __restrict__ bias,
               void* __restrict__ Yout, int obase)
{
    constexpr int PA = KA/2, PB = KB/2;
    constexpr bool FULLALL = (KA == 5 && KB == 5);
    constexpr int NFC = 13;
    constexpr int NFO = (KA*KB*16 + 31)/32;
    __shared__ __align__(16) char lbuf[12800];

    const int tid = threadIdx.x, lane = tid & 63, wid = tid >> 6;
    int blk = (blockIdx.x & 7) * (gridDim.x >> 3) + (blockIdx.x >> 3);
    const int w1 = blk & 15, h1 = (blk >> 4) & 15, b = blk >> 8;
    const int g = lane >> 4, lane15 = lane & 15;

    for (int i = tid; i < 3200; i += 256) reinterpret_cast<int*>(lbuf)[i] = 0;

    unsigned offsC[NFC];
    #pragma unroll
    for (int f = 0; f < NFC; ++f) {
        int kk = f*32 + g*8;
        unsigned off = 0;
        if (kk < 400) {
            int sp = kk >> 4, half = (kk >> 3) & 1;
            int dsh = sp/5 - 2, dsw = sp%5 - 2;
            off = (unsigned)(half*6400 + ((dsh+2)*20 + (dsw+2))*16);
        }
        offsC[f] = off;
    }
    unsigned offsO[NFO];
    if (!FULLALL) {
        #pragma unroll
        for (int f = 0; f < NFO; ++f) {
            int kk = f*32 + g*8;
            unsigned off = 0;
            if (kk < KA*KB*16) {
                int sp = kk >> 4, half = (kk >> 3) & 1;
                int dsh = sp/KB - PA, dsw = sp%KB - PB;
                off = (unsigned)(half*6400 + ((dsh+2)*20 + (dsw+2))*16);
            }
            offsO[f] = off;
        }
    }

    f32x4 acc[4] = {{0,0,0,0},{0,0,0,0},{0,0,0,0},{0,0,0,0}};
    const unsigned aterm = (unsigned)(lane15*16 + wid*4*320);

    const int dst0 = (tid&1)*6400 + (((tid>>1)>>4)+2)*320 + (((tid>>1)&15)+2)*16;
    const int dst1 = dst0 + 2560;

    short8 st0, st1;
    load_plane_regs(X, b, h1, w1, 0, tid, st0, st1);

    for (int p = 0; p < 25; ++p) {
        __syncthreads();
        *reinterpret_cast<short8*>(lbuf + dst0) = st0;
        *reinterpret_cast<short8*>(lbuf + dst1) = st1;
        __syncthreads();
        if (p < 24) load_plane_regs(X, b, h1, w1, p+1, tid, st0, st1);

        int pi = p/5, pj = p%5;
        const short8* bp = reinterpret_cast<const short8*>(Bws) + (size_t)p*13*64 + lane;
        bool center = FULLALL || (pi >= 2-PA && pi <= 2+PA && pj >= 2-PB && pj <= 2+PB);
        if (center) {
            #pragma unroll
            for (int f = 0; f < NFC; ++f) {
                short8 bf = bp[f*64];
                #pragma unroll
                for (int mt = 0; mt < 4; ++mt) {
                    short8 a = *reinterpret_cast<const short8*>(lbuf + offsC[f] + aterm + mt*320);
                    acc[mt] = __builtin_amdgcn_mfma_f32_16x16x32_bf16(a, bf, acc[mt], 0, 0, 0);
                }
            }
        } else {
            #pragma unroll
            for (int f = 0; f < NFO; ++f) {
                short8 bf = bp[f*64];
                #pragma unroll
                for (int mt = 0; mt < 4; ++mt) {
                    short8 a = *reinterpret_cast<const short8*>(lbuf + offsO[f] + aterm + mt*320);
                    acc[mt] = __builtin_amdgcn_mfma_f32_16x16x32_bf16(a, bf, acc[mt], 0, 0, 0);
                }
            }
        }
    }

    const int o = lane15 & 7;
    const float bv = (o < O) ? bias[o] : 0.f;
    #pragma unroll
    for (int mt = 0; mt < 4; ++mt) {
        #pragma unroll
        for (int r = 0; r < 4; ++r) {
            float own = acc[mt][r];
            float oth = __shfl_xor(own, 8);
            if (lane15 < 8 && o < O) {
                float y = fmaxf(own + bv, 0.f) + fmaxf(oth + bv, 0.f);
                int h2 = wid*4 + mt, w2 = g*4 + r;
                size_t pos = (((size_t)b*256 + h1*16 + w1) << 8) + h2*16 + w2;
                if (OUTBF16)
                    reinterpret_cast<__hip_bfloat16*>(Yout)[pos*16 + obase + o] = __float2bfloat16(y);
                else
                    reinterpret_cast<float*>(Yout)[pos] = y;
            }
        }
    }
}

// ---------------------------------------------------------------------------
// L3 delta-packed MFMA, K-SPLIT across waves (r9, measured ~28 us)
// ---------------------------------------------------------------------------
__device__ inline void load_plane_l3(const __hip_bfloat16* __restrict__ X,
                                     int b, int h1, int w1, int p, int tid,
                                     short8& s0, short8& s1)
{
    int pi = p/5, pj = p%5;
    int hh = h1 + pi - 2, ww = w1 + pj - 2;
    short8 z = {};
    if ((unsigned)hh < 16u && (unsigned)ww < 16u) {
        const short8* src = reinterpret_cast<const short8*>(X)
                          + ((size_t)((b*16 + hh)*16 + ww) << 9);
        s0 = src[tid*2];
        s1 = src[tid*2 + 1];
    } else { s0 = z; s1 = z; }
}

__global__ __launch_bounds__(256)
void conv_mfma_l3k(const __hip_bfloat16* __restrict__ X,
                   const __hip_bfloat16* __restrict__ Bf,
                   const float* __restrict__ bias,
                   float* __restrict__ Yout)
{
    __shared__ __align__(16) char lbuf[16384];

    const int tid = threadIdx.x, lane = tid & 63, wid = tid >> 6;
    int blk = (blockIdx.x & 7) * (gridDim.x >> 3) + (blockIdx.x >> 3);
    const int w1 = blk & 15, h1 = (blk >> 4) & 15, b = blk >> 8;
    const int g = lane >> 4, lane15 = lane & 15;

    for (int i = tid; i < 3200; i += 256) reinterpret_cast<int*>(lbuf)[i] = 0;

    unsigned offA[5];
    #pragma unroll
    for (int fl = 0; fl < 5; ++fl) {
        int fg = wid*5 + fl;
        int s     = fg*2 + (g >> 1);
        int chalf = g & 1;
        int shidx = s >> 3;
        int swidx = s & 7;
        int row   = lane15 + shidx;
        unsigned a = (unsigned)(row*640 + swidx*32 + chalf*16);
        offA[fl] = a ^ (((unsigned)(row & 7)) << 4);
    }

    const int srow = (tid >> 4) + 2;
    const unsigned wswz = ((unsigned)(srow & 7)) << 4;
    const unsigned wp0 = ((unsigned)(srow*640 + ((tid & 15) + 2)*32)) ^ wswz;

    f32x4 acc[4] = {{0,0,0,0},{0,0,0,0},{0,0,0,0},{0,0,0,0}};

    short8 st0, st1;
    load_plane_l3(X, b, h1, w1, 0, tid, st0, st1);

    for (int p = 0; p < 25; ++p) {
        __syncthreads();
        *reinterpret_cast<short8*>(lbuf + wp0)        = st0;
        *reinterpret_cast<short8*>(lbuf + (wp0^16u))  = st1;
        __syncthreads();
        if (p < 24) load_plane_l3(X, b, h1, w1, p+1, tid, st0, st1);

        const short8* bpp = reinterpret_cast<const short8*>(Bf)
                          + (size_t)p*20*64 + (size_t)wid*5*64 + lane;
        #pragma unroll
        for (int fl = 0; fl < 5; ++fl) {
            short8 bf = bpp[fl*64];
            #pragma unroll
            for (int q = 0; q < 4; ++q) {
                short8 a = *reinterpret_cast<const short8*>(lbuf + offA[fl] + q*128);
                acc[q] = __builtin_amdgcn_mfma_f32_16x16x32_bf16(a, bf, acc[q], 0, 0, 0);
            }
        }
    }

    __syncthreads();
    f32x4* red = reinterpret_cast<f32x4*>(lbuf);
    #pragma unroll
    for (int q = 0; q < 4; ++q)
        red[(wid*4 + q)*64 + lane] = acc[q];
    __syncthreads();

    f32x4 tot = red[wid*64 + lane];
    #pragma unroll
    for (int w = 1; w < 4; ++w)
        tot = tot + red[(w*4 + wid)*64 + lane];

    const float bv = bias[0];
    #pragma unroll
    for (int r = 0; r < 4; ++r) {
        float own = tot[r];
        float oth = __shfl_xor(own, 4);
        if (lane15 < 4) {
            float y = fmaxf(own + bv, 0.f) + fmaxf(oth + bv, 0.f);
            int h2 = g*4 + r, w2v = wid*4 + lane15;
            Yout[((size_t)blk << 8) + h2*16 + w2v] = y;
        }
    }
}

// ---------------------------------------------------------------------------
extern "C" void kernel_launch(void* const* d_in, const int* in_sizes, int n_in,
                              void* d_out, int out_size, void* d_ws, size_t ws_size,
                              hipStream_t stream) {
    const float* x   = (const float*)d_in[0];
    const float* w00 = (const float*)d_in[1];
    const float* b00 = (const float*)d_in[2];
    const float* w01 = (const float*)d_in[3];
    const float* b01 = (const float*)d_in[4];
    const float* w10 = (const float*)d_in[5];
    const float* b10 = (const float*)d_in[6];
    const float* w11 = (const float*)d_in[7];
    const float* b11 = (const float*)d_in[8];
    const float* w2  = (const float*)d_in[9];
    const float* b2  = (const float*)d_in[10];

    const int B = in_sizes[0] / SP;   // 4

    __hip_bfloat16* X1   = (__hip_bfloat16*)d_ws;                 // B*SP*16
    __hip_bfloat16* X2   = X1 + (size_t)B * SP * 16;              // B*SP*16
    __hip_bfloat16* Bw10 = X2 + (size_t)B * SP * 16;              // 25*13*64*8
    __hip_bfloat16* Bw11 = Bw10 + 25*13*64*8;
    __hip_bfloat16* Bl3  = Bw11 + 25*13*64*8;                     // 25*20*64*8
    __hip_bfloat16* Bl1a = Bl3  + 25*20*64*8;                     // 25*64*8
    __hip_bfloat16* Bl1b = Bl1a + 25*64*8;
    __hip_bfloat16* Xim  = Bl1b + 25*64*8;                        // B*SP*32

    const int ximTotal = B * SP * 4;
    hipLaunchKernelGGL(build_xim, dim3((ximTotal + 255)/256), dim3(256), 0, stream,
                       x, Xim, ximTotal);

    hipLaunchKernelGGL(fused_prep, dim3(300), dim3(256), 0, stream,
                       w00, w01, w10, w11, w2, Bl1a, Bl1b, Bw10, Bw11, Bl3);

    dim3 block(256), grid(B * 256);
    hipLaunchKernelGGL(conv_mfma_l1, grid, block, 0, stream,
                       Xim, Bl1a, Bl1b, b00, b01, X1);

    hipLaunchKernelGGL((conv_mfma<8,3,3,true>),  grid, block, 0, stream,
                       X1, Bw10, b10, (void*)X2, 0);
    hipLaunchKernelGGL((conv_mfma<8,5,5,true>),  grid, block, 0, stream,
                       X1, Bw11, b11, (void*)X2, 8);

    hipLaunchKernelGGL(conv_mfma_l3k, grid, block, 0, stream,
                       X2, Bl3, b2, (float*)d_out);
}

// Round 15
// 206.818 us; speedup vs baseline: 1.3447x; 1.0274x over previous
//
#include <hip/hip_runtime.h>
#include <hip/hip_bf16.h>

#define SS 16
#define SP 65536   // 16^4

typedef __attribute__((ext_vector_type(8))) short short8;
typedef __attribute__((ext_vector_type(4))) float f32x4;

// ---------------------------------------------------------------------------
// Xim: [b][h1][w1][h2][w2][32] bf16. Slot s = k*5+l <-> inner shift (k-2, l-2)
// ---------------------------------------------------------------------------
__global__ __launch_bounds__(256)
void build_xim(const float* __restrict__ X, __hip_bfloat16* __restrict__ Xim, int total)
{
    int t = blockIdx.x * 256 + threadIdx.x;       // t = pos*4 + g
    if (t >= total) return;
    int g   = t & 3;
    int pos = t >> 2;
    int w2 = pos & 15, h2 = (pos >> 4) & 15;
    const float* xp = X + ((size_t)(pos >> 8) << 8);
    __hip_bfloat16 vals[8];
    #pragma unroll
    for (int j = 0; j < 8; ++j) {
        int s = g*8 + j;
        float v = 0.f;
        if (s < 25) {
            int hh = h2 + s/5 - 2, ww = w2 + s%5 - 2;
            if ((unsigned)hh < 16u && (unsigned)ww < 16u)
                v = xp[hh*16 + ww];
        }
        vals[j] = __float2bfloat16(v);
    }
    *reinterpret_cast<short8*>(Xim + (size_t)t * 8) = *reinterpret_cast<const short8*>(vals);
}

// ---------------------------------------------------------------------------
// Prep device functions (bodies of the verified r3/r5 prep kernels)
// ---------------------------------------------------------------------------
template<int KA, int KB>
__device__ inline void prep_bl1_dev(int t, const float* __restrict__ W,
                                    __hip_bfloat16* __restrict__ Bf)
{
    constexpr int PA = KA/2, PB = KB/2;
    int lane = t & 63, p = t >> 6;
    int pi = p/5, pj = p%5;
    int n = lane & 15;
    __hip_bfloat16 vals[8];
    #pragma unroll
    for (int j = 0; j < 8; ++j) {
        int s = (lane >> 4)*8 + j;
        float v = 0.f;
        if (s < 25) {
            int kk = s/5, ll = s%5;
            if (n < 8) {
                int i = pi - 2 + PA, jj = pj - 2 + PB;
                if ((unsigned)i < (unsigned)KA && (unsigned)jj < (unsigned)KB)
                    v = W[(((n*KA + i)*KB + jj)*5 + kk)*5 + ll];
            } else {
                int k2 = kk - 2 + PA, l2 = ll - 2 + PB;
                if ((unsigned)k2 < (unsigned)KA && (unsigned)l2 < (unsigned)KB)
                    v = W[((((n-8)*KA + k2)*KB + l2)*5 + pi)*5 + pj];
            }
        }
        vals[j] = __float2bfloat16(v);
    }
    *reinterpret_cast<short8*>(Bf + (size_t)t * 8) = *reinterpret_cast<const short8*>(vals);
}

// r3 compact-stream L2 B fragments (center: 400-slot union; else KA*KB*16)
template<int O, int KA, int KB>
__device__ inline void prep_bfrag_dev(int t, const float* __restrict__ W,
                                      __hip_bfloat16* __restrict__ Bws)
{
    constexpr int PA = KA/2, PB = KB/2;
    int lane = t & 63;
    int f = (t >> 6) % 13;
    int p = t / (64*13);
    int pi = p/5, pj = p%5;
    bool c1a = (pi >= 2-PA && pi <= 2+PA && pj >= 2-PB && pj <= 2+PB);
    int slen = c1a ? 400 : KA*KB*16;
    int n = lane & 15;
    __hip_bfloat16 vals[8];
    #pragma unroll
    for (int j = 0; j < 8; ++j) {
        int kk = f*32 + ((lane>>4)*8) + j;
        float v = 0.f;
        if (kk < slen) {
            int sp = kk >> 4, c = kk & 15;
            int dsh, dsw;
            if (c1a) { dsh = sp/5 - 2;  dsw = sp%5 - 2;  }
            else     { dsh = sp/KB - PA; dsw = sp%KB - PB; }
            if (n < 8) {
                if (c1a && n < O)
                    v = W[((((size_t)(n*16 + c)*KA + (pi-2+PA))*KB + (pj-2+PB))*5 + (dsh+2))*5 + (dsw+2)];
            } else {
                int o = n - 8;
                if (o < O && dsh >= -PA && dsh <= PA && dsw >= -PB && dsw <= PB)
                    v = W[((((size_t)(o*16 + c)*KA + (dsh+PA))*KB + (dsw+PB))*5 + pi)*5 + pj];
            }
        }
        vals[j] = __float2bfloat16(v);
    }
    *reinterpret_cast<short8*>(Bws + (size_t)t * 8) = *reinterpret_cast<const short8*>(vals);
}

// L3 delta-packed B fragments: 20 frags/plane, k = (s_h 5, s_w' 8, c 16)
__device__ inline void prep_bl3_dev(int t, const float* __restrict__ W,
                                    __hip_bfloat16* __restrict__ Bf)
{
    int lane = t & 63;
    int f = (t >> 6) % 20;
    int p = t / (64*20);
    int pi = p/5, pj = p%5;
    int n = lane & 15;
    __hip_bfloat16 vals[8];
    #pragma unroll
    for (int j = 0; j < 8; ++j) {
        int kk = f*32 + ((lane>>4)*8) + j;    // < 640
        int s = kk >> 4, c = kk & 15;
        int shidx = s >> 3;                   // 0..4  (s_h = shidx-2)
        int swidx = s & 7;                    // 0..7  (s_w' = swidx-2)
        float v = 0.f;
        if (n < 8) {
            int dlt = n & 3;
            int sw = swidx - 2 - dlt;
            int sh = shidx - 2;
            if (sw >= -2 && sw <= 2) {
                if (n < 4)
                    v = W[(((c*5 + pi)*5 + pj)*5 + (sh+2))*5 + (sw+2)];
                else
                    v = W[(((c*5 + (sh+2))*5 + (sw+2))*5 + pi)*5 + pj];
            }
        }
        vals[j] = __float2bfloat16(v);
    }
    *reinterpret_cast<short8*>(Bf + (size_t)t * 8) = *reinterpret_cast<const short8*>(vals);
}

// One dispatch for all 5 prep tables (76800 threads total)
__global__ __launch_bounds__(256)
void fused_prep(const float* __restrict__ w00, const float* __restrict__ w01,
                const float* __restrict__ w10, const float* __restrict__ w11,
                const float* __restrict__ w2,
                __hip_bfloat16* __restrict__ Bl1a, __hip_bfloat16* __restrict__ Bl1b,
                __hip_bfloat16* __restrict__ Bw10, __hip_bfloat16* __restrict__ Bw11,
                __hip_bfloat16* __restrict__ Bl3)
{
    int t = blockIdx.x * 256 + threadIdx.x;
    if (t < 1600)  { prep_bl1_dev<3,3>(t, w00, Bl1a); return; }
    t -= 1600;
    if (t < 1600)  { prep_bl1_dev<5,5>(t, w01, Bl1b); return; }
    t -= 1600;
    if (t < 20800) { prep_bfrag_dev<8,3,3>(t, w10, Bw10); return; }
    t -= 20800;
    if (t < 20800) { prep_bfrag_dev<8,5,5>(t, w11, Bw11); return; }
    t -= 20800;
    if (t < 32000) { prep_bl3_dev(t, w2, Bl3); }
}

// ---------------------------------------------------------------------------
// Layer-1 MFMA: no LDS, A direct from Xim, two B streams share A. (r3, fast)
// ---------------------------------------------------------------------------
__global__ __launch_bounds__(256)
void conv_mfma_l1(const __hip_bfloat16* __restrict__ Xim,
                  const __hip_bfloat16* __restrict__ B0,
                  const __hip_bfloat16* __restrict__ B1,
                  const float* __restrict__ bias0,
                  const float* __restrict__ bias1,
                  __hip_bfloat16* __restrict__ Y)
{
    const int tid = threadIdx.x, lane = tid & 63, wid = tid >> 6;
    int blk = (blockIdx.x & 7) * (gridDim.x >> 3) + (blockIdx.x >> 3);
    const int w1 = blk & 15, h1 = (blk >> 4) & 15, b = blk >> 8;
    const int g = lane >> 4, lane15 = lane & 15;

    f32x4 acc0[4] = {{0,0,0,0},{0,0,0,0},{0,0,0,0},{0,0,0,0}};
    f32x4 acc1[4] = {{0,0,0,0},{0,0,0,0},{0,0,0,0},{0,0,0,0}};
    const short8* BB0 = reinterpret_cast<const short8*>(B0);
    const short8* BB1 = reinterpret_cast<const short8*>(B1);

    for (int p = 0; p < 25; ++p) {
        int hh = h1 + p/5 - 2, ww = w1 + p%5 - 2;
        if ((unsigned)hh >= 16u || (unsigned)ww >= 16u) continue;
        const short8* ap = reinterpret_cast<const short8*>(Xim)
                         + ((size_t)((b*16 + hh)*16 + ww) << 10);
        short8 b0 = BB0[p*64 + lane];
        short8 b1 = BB1[p*64 + lane];
        #pragma unroll
        for (int mt = 0; mt < 4; ++mt) {
            short8 a = ap[(((wid*4 + mt)*16 + lane15) << 2) + g];
            acc0[mt] = __builtin_amdgcn_mfma_f32_16x16x32_bf16(a, b0, acc0[mt], 0, 0, 0);
            acc1[mt] = __builtin_amdgcn_mfma_f32_16x16x32_bf16(a, b1, acc1[mt], 0, 0, 0);
        }
    }

    const int o = lane15 & 7;
    const float bv0 = bias0[o], bv1 = bias1[o];
    #pragma unroll
    for (int mt = 0; mt < 4; ++mt) {
        #pragma unroll
        for (int r = 0; r < 4; ++r) {
            float own0 = acc0[mt][r], oth0 = __shfl_xor(own0, 8);
            float own1 = acc1[mt][r], oth1 = __shfl_xor(own1, 8);
            if (lane15 < 8) {
                float y0 = fmaxf(own0 + bv0, 0.f) + fmaxf(oth0 + bv0, 0.f);
                float y1 = fmaxf(own1 + bv1, 0.f) + fmaxf(oth1 + bv1, 0.f);
                int h2 = wid*4 + mt, w2v = g*4 + r;
                size_t pos = ((size_t)blk << 8) + h2*16 + w2v;
                Y[pos*16 + o]     = __float2bfloat16(y0);
                Y[pos*16 + 8 + o] = __float2bfloat16(y1);
            }
        }
    }
}

// ---------------------------------------------------------------------------
// Layer-2 MFMA conv (r3 split template). NEW in r15: FULLALL (w11) path gets
// a rotating register B-prefetch — frag f of plane p+1 is loaded right after
// frag f of plane p's last MFMA (B-loads are barrier-independent, so each
// load has a full plane of MFMAs to complete). +52 VGPR, literal-indexed.
// w10 path unchanged.
// ---------------------------------------------------------------------------
__device__ inline void load_plane_regs(const __hip_bfloat16* __restrict__ X,
                                       int b, int h1, int w1, int p, int tid,
                                       short8& s0, short8& s1)
{
    int pi = p/5, pj = p%5;
    int hh = h1 + pi - 2, ww = w1 + pj - 2;
    short8 z = {};
    if ((unsigned)hh < 16u && (unsigned)ww < 16u) {
        const short8* src = reinterpret_cast<const short8*>(X)
                          + ((size_t)((b*16 + hh)*16 + ww) << 9);
        s0 = src[tid];
        s1 = src[tid + 256];
    } else { s0 = z; s1 = z; }
}

template<int O, int KA, int KB, bool OUTBF16>
__global__ __launch_bounds__(256)
void conv_mfma(const __hip_bfloat16* __restrict__ X,
               const __hip_bfloat16* __restrict__ Bws,
               const float* __restrict__ bias,
               void* __restrict__ Yout, int obase)
{
    constexpr int PA = KA/2, PB = KB/2;
    constexpr bool FULLALL = (KA == 5 && KB == 5);
    constexpr int NFC = 13;
    constexpr int NFO = (KA*KB*16 + 31)/32;
    __shared__ __align__(16) char lbuf[12800];

    const int tid = threadIdx.x, lane = tid & 63, wid = tid >> 6;
    int blk = (blockIdx.x & 7) * (gridDim.x >> 3) + (blockIdx.x >> 3);
    const int w1 = blk & 15, h1 = (blk >> 4) & 15, b = blk >> 8;
    const int g = lane >> 4, lane15 = lane & 15;

    for (int i = tid; i < 3200; i += 256) reinterpret_cast<int*>(lbuf)[i] = 0;

    unsigned offsC[NFC];
    #pragma unroll
    for (int f = 0; f < NFC; ++f) {
        int kk = f*32 + g*8;
        unsigned off = 0;
        if (kk < 400) {
            int sp = kk >> 4, half = (kk >> 3) & 1;
            int dsh = sp/5 - 2, dsw = sp%5 - 2;
            off = (unsigned)(half*6400 + ((dsh+2)*20 + (dsw+2))*16);
        }
        offsC[f] = off;
    }
    unsigned offsO[NFO];
    if (!FULLALL) {
        #pragma unroll
        for (int f = 0; f < NFO; ++f) {
            int kk = f*32 + g*8;
            unsigned off = 0;
            if (kk < KA*KB*16) {
                int sp = kk >> 4, half = (kk >> 3) & 1;
                int dsh = sp/KB - PA, dsw = sp%KB - PB;
                off = (unsigned)(half*6400 + ((dsh+2)*20 + (dsw+2))*16);
            }
            offsO[f] = off;
        }
    }

    f32x4 acc[4] = {{0,0,0,0},{0,0,0,0},{0,0,0,0},{0,0,0,0}};
    const unsigned aterm = (unsigned)(lane15*16 + wid*4*320);

    const int dst0 = (tid&1)*6400 + (((tid>>1)>>4)+2)*320 + (((tid>>1)&15)+2)*16;
    const int dst1 = dst0 + 2560;

    short8 st0, st1;
    load_plane_regs(X, b, h1, w1, 0, tid, st0, st1);

    if (FULLALL) {
        // w11 path: rotating register B-prefetch.
        const short8* BBase = reinterpret_cast<const short8*>(Bws) + lane;
        short8 bfr[NFC];
        #pragma unroll
        for (int f = 0; f < NFC; ++f) bfr[f] = BBase[f*64];   // plane 0

        for (int p = 0; p < 25; ++p) {
            __syncthreads();
            *reinterpret_cast<short8*>(lbuf + dst0) = st0;
            *reinterpret_cast<short8*>(lbuf + dst1) = st1;
            __syncthreads();
            if (p < 24) load_plane_regs(X, b, h1, w1, p+1, tid, st0, st1);

            const int pn = (p < 24) ? p + 1 : 24;   // last-plane reload is harmless
            const short8* bpn = BBase + (size_t)pn*13*64;
            #pragma unroll
            for (int f = 0; f < NFC; ++f) {
                short8 bf = bfr[f];
                #pragma unroll
                for (int mt = 0; mt < 4; ++mt) {
                    short8 a = *reinterpret_cast<const short8*>(lbuf + offsC[f] + aterm + mt*320);
                    acc[mt] = __builtin_amdgcn_mfma_f32_16x16x32_bf16(a, bf, acc[mt], 0, 0, 0);
                }
                bfr[f] = bpn[f*64];                 // prefetch next plane's frag f
            }
        }
    } else {
        // w10 path: unchanged r3 body.
        for (int p = 0; p < 25; ++p) {
            __syncthreads();
            *reinterpret_cast<short8*>(lbuf + dst0) = st0;
            *reinterpret_cast<short8*>(lbuf + dst1) = st1;
            __syncthreads();
            if (p < 24) load_plane_regs(X, b, h1, w1, p+1, tid, st0, st1);

            int pi = p/5, pj = p%5;
            const short8* bp = reinterpret_cast<const short8*>(Bws) + (size_t)p*13*64 + lane;
            bool center = (pi >= 2-PA && pi <= 2+PA && pj >= 2-PB && pj <= 2+PB);
            if (center) {
                #pragma unroll
                for (int f = 0; f < NFC; ++f) {
                    short8 bf = bp[f*64];
                    #pragma unroll
                    for (int mt = 0; mt < 4; ++mt) {
                        short8 a = *reinterpret_cast<const short8*>(lbuf + offsC[f] + aterm + mt*320);
                        acc[mt] = __builtin_amdgcn_mfma_f32_16x16x32_bf16(a, bf, acc[mt], 0, 0, 0);
                    }
                }
            } else {
                #pragma unroll
                for (int f = 0; f < NFO; ++f) {
                    short8 bf = bp[f*64];
                    #pragma unroll
                    for (int mt = 0; mt < 4; ++mt) {
                        short8 a = *reinterpret_cast<const short8*>(lbuf + offsO[f] + aterm + mt*320);
                        acc[mt] = __builtin_amdgcn_mfma_f32_16x16x32_bf16(a, bf, acc[mt], 0, 0, 0);
                    }
                }
            }
        }
    }

    const int o = lane15 & 7;
    const float bv = (o < O) ? bias[o] : 0.f;
    #pragma unroll
    for (int mt = 0; mt < 4; ++mt) {
        #pragma unroll
        for (int r = 0; r < 4; ++r) {
            float own = acc[mt][r];
            float oth = __shfl_xor(own, 8);
            if (lane15 < 8 && o < O) {
                float y = fmaxf(own + bv, 0.f) + fmaxf(oth + bv, 0.f);
                int h2 = wid*4 + mt, w2 = g*4 + r;
                size_t pos = (((size_t)b*256 + h1*16 + w1) << 8) + h2*16 + w2;
                if (OUTBF16)
                    reinterpret_cast<__hip_bfloat16*>(Yout)[pos*16 + obase + o] = __float2bfloat16(y);
                else
                    reinterpret_cast<float*>(Yout)[pos] = y;
            }
        }
    }
}

// ---------------------------------------------------------------------------
// L3 delta-packed MFMA, K-SPLIT across waves (r9, measured ~28 us)
// ---------------------------------------------------------------------------
__device__ inline void load_plane_l3(const __hip_bfloat16* __restrict__ X,
                                     int b, int h1, int w1, int p, int tid,
                                     short8& s0, short8& s1)
{
    int pi = p/5, pj = p%5;
    int hh = h1 + pi - 2, ww = w1 + pj - 2;
    short8 z = {};
    if ((unsigned)hh < 16u && (unsigned)ww < 16u) {
        const short8* src = reinterpret_cast<const short8*>(X)
                          + ((size_t)((b*16 + hh)*16 + ww) << 9);
        s0 = src[tid*2];
        s1 = src[tid*2 + 1];
    } else { s0 = z; s1 = z; }
}

__global__ __launch_bounds__(256)
void conv_mfma_l3k(const __hip_bfloat16* __restrict__ X,
                   const __hip_bfloat16* __restrict__ Bf,
                   const float* __restrict__ bias,
                   float* __restrict__ Yout)
{
    __shared__ __align__(16) char lbuf[16384];

    const int tid = threadIdx.x, lane = tid & 63, wid = tid >> 6;
    int blk = (blockIdx.x & 7) * (gridDim.x >> 3) + (blockIdx.x >> 3);
    const int w1 = blk & 15, h1 = (blk >> 4) & 15, b = blk >> 8;
    const int g = lane >> 4, lane15 = lane & 15;

    for (int i = tid; i < 3200; i += 256) reinterpret_cast<int*>(lbuf)[i] = 0;

    unsigned offA[5];
    #pragma unroll
    for (int fl = 0; fl < 5; ++fl) {
        int fg = wid*5 + fl;
        int s     = fg*2 + (g >> 1);
        int chalf = g & 1;
        int shidx = s >> 3;
        int swidx = s & 7;
        int row   = lane15 + shidx;
        unsigned a = (unsigned)(row*640 + swidx*32 + chalf*16);
        offA[fl] = a ^ (((unsigned)(row & 7)) << 4);
    }

    const int srow = (tid >> 4) + 2;
    const unsigned wswz = ((unsigned)(srow & 7)) << 4;
    const unsigned wp0 = ((unsigned)(srow*640 + ((tid & 15) + 2)*32)) ^ wswz;

    f32x4 acc[4] = {{0,0,0,0},{0,0,0,0},{0,0,0,0},{0,0,0,0}};

    short8 st0, st1;
    load_plane_l3(X, b, h1, w1, 0, tid, st0, st1);

    for (int p = 0; p < 25; ++p) {
        __syncthreads();
        *reinterpret_cast<short8*>(lbuf + wp0)        = st0;
        *reinterpret_cast<short8*>(lbuf + (wp0^16u))  = st1;
        __syncthreads();
        if (p < 24) load_plane_l3(X, b, h1, w1, p+1, tid, st0, st1);

        const short8* bpp = reinterpret_cast<const short8*>(Bf)
                          + (size_t)p*20*64 + (size_t)wid*5*64 + lane;
        #pragma unroll
        for (int fl = 0; fl < 5; ++fl) {
            short8 bf = bpp[fl*64];
            #pragma unroll
            for (int q = 0; q < 4; ++q) {
                short8 a = *reinterpret_cast<const short8*>(lbuf + offA[fl] + q*128);
                acc[q] = __builtin_amdgcn_mfma_f32_16x16x32_bf16(a, bf, acc[q], 0, 0, 0);
            }
        }
    }

    __syncthreads();
    f32x4* red = reinterpret_cast<f32x4*>(lbuf);
    #pragma unroll
    for (int q = 0; q < 4; ++q)
        red[(wid*4 + q)*64 + lane] = acc[q];
    __syncthreads();

    f32x4 tot = red[wid*64 + lane];
    #pragma unroll
    for (int w = 1; w < 4; ++w)
        tot = tot + red[(w*4 + wid)*64 + lane];

    const float bv = bias[0];
    #pragma unroll
    for (int r = 0; r < 4; ++r) {
        float own = tot[r];
        float oth = __shfl_xor(own, 4);
        if (lane15 < 4) {
            float y = fmaxf(own + bv, 0.f) + fmaxf(oth + bv, 0.f);
            int h2 = g*4 + r, w2v = wid*4 + lane15;
            Yout[((size_t)blk << 8) + h2*16 + w2v] = y;
        }
    }
}

// ---------------------------------------------------------------------------
extern "C" void kernel_launch(void* const* d_in, const int* in_sizes, int n_in,
                              void* d_out, int out_size, void* d_ws, size_t ws_size,
                              hipStream_t stream) {
    const float* x   = (const float*)d_in[0];
    const float* w00 = (const float*)d_in[1];
    const float* b00 = (const float*)d_in[2];
    const float* w01 = (const float*)d_in[3];
    const float* b01 = (const float*)d_in[4];
    const float* w10 = (const float*)d_in[5];
    const float* b10 = (const float*)d_in[6];
    const float* w11 = (const float*)d_in[7];
    const float* b11 = (const float*)d_in[8];
    const float* w2  = (const float*)d_in[9];
    const float* b2  = (const float*)d_in[10];

    const int B = in_sizes[0] / SP;   // 4

    __hip_bfloat16* X1   = (__hip_bfloat16*)d_ws;                 // B*SP*16
    __hip_bfloat16* X2   = X1 + (size_t)B * SP * 16;              // B*SP*16
    __hip_bfloat16* Bw10 = X2 + (size_t)B * SP * 16;              // 25*13*64*8
    __hip_bfloat16* Bw11 = Bw10 + 25*13*64*8;
    __hip_bfloat16* Bl3  = Bw11 + 25*13*64*8;                     // 25*20*64*8
    __hip_bfloat16* Bl1a = Bl3  + 25*20*64*8;                     // 25*64*8
    __hip_bfloat16* Bl1b = Bl1a + 25*64*8;
    __hip_bfloat16* Xim  = Bl1b + 25*64*8;                        // B*SP*32

    const int ximTotal = B * SP * 4;
    hipLaunchKernelGGL(build_xim, dim3((ximTotal + 255)/256), dim3(256), 0, stream,
                       x, Xim, ximTotal);

    hipLaunchKernelGGL(fused_prep, dim3(300), dim3(256), 0, stream,
                       w00, w01, w10, w11, w2, Bl1a, Bl1b, Bw10, Bw11, Bl3);

    dim3 block(256), grid(B * 256);
    hipLaunchKernelGGL(conv_mfma_l1, grid, block, 0, stream,
                       Xim, Bl1a, Bl1b, b00, b01, X1);

    hipLaunchKernelGGL((conv_mfma<8,3,3,true>),  grid, block, 0, stream,
                       X1, Bw10, b10, (void*)X2, 0);
    hipLaunchKernelGGL((conv_mfma<8,5,5,true>),  grid, block, 0, stream,
                       X1, Bw11, b11, (void*)X2, 8);

    hipLaunchKernelGGL(conv_mfma_l3k, grid, block, 0, stream,
                       X2, Bl3, b2, (float*)d_out);
}